// Round 1
// baseline (922.080 us; speedup 1.0000x reference)
//
#include <hip/hip_runtime.h>

// Problem constants (from reference): V=2048, G=48, K=128, B=1024
#define V 2048
#define G 48
#define K 128
#define B 1024

// Workspace layout (ints):
//   [0, B)            word_idx[b]
//   [B, B+V)          needed[v]  (0/1 bitmap, must be zeroed each launch)
//   [B+V, B+V+G*V)    tab[g*V+v] = perm index (only written for needed v)

__global__ void zero_needed(int* __restrict__ needed) {
    int i = blockIdx.x * blockDim.x + threadIdx.x;
    if (i < V) needed[i] = 0;
}

// One block (256 threads) per batch row: find the 1.0 in the one-hot input.
// Exactly one thread finds it -> no reduction needed.
__global__ void find_word_idx(const float* __restrict__ input,
                              int* __restrict__ word_idx,
                              int* __restrict__ needed) {
    int b = blockIdx.x;
    int t = threadIdx.x;
    const float* row = input + (size_t)b * V;
    int base = t * 8;  // 256 threads * 8 floats = 2048
    float4 x0 = *(const float4*)(row + base);
    float4 x1 = *(const float4*)(row + base + 4);
    int hit = -1;
    if      (x0.x > 0.5f) hit = base + 0;
    else if (x0.y > 0.5f) hit = base + 1;
    else if (x0.z > 0.5f) hit = base + 2;
    else if (x0.w > 0.5f) hit = base + 3;
    else if (x1.x > 0.5f) hit = base + 4;
    else if (x1.y > 0.5f) hit = base + 5;
    else if (x1.z > 0.5f) hit = base + 6;
    else if (x1.w > 0.5f) hit = base + 7;
    if (hit >= 0) {
        word_idx[b] = hit;
        needed[hit] = 1;  // benign same-value race across blocks
    }
}

// One wave (64 lanes) per (g, v) row of perms; skip rows nobody needs.
// Early-exit once the 1.0 is found (expected halfway through the row).
__global__ void scan_perms(const float* __restrict__ perms,
                           const int* __restrict__ needed,
                           int* __restrict__ tab) {
    int wid  = (blockIdx.x * blockDim.x + threadIdx.x) >> 6;  // global wave id
    int lane = threadIdx.x & 63;
    if (wid >= G * V) return;
    int g = wid >> 11;        // / V
    int v = wid & (V - 1);    // % V
    if (!needed[v]) return;
    const float* row = perms + ((size_t)g * V + (size_t)v) * V;
    // 2048 floats, 64 lanes * float4 = 256 floats per iteration, 8 iters.
    for (int it = 0; it < 8; ++it) {
        int base = it * 256 + lane * 4;
        float4 x = *(const float4*)(row + base);
        int hit = -1;
        if      (x.x > 0.5f) hit = base + 0;
        else if (x.y > 0.5f) hit = base + 1;
        else if (x.z > 0.5f) hit = base + 2;
        else if (x.w > 0.5f) hit = base + 3;
        if (hit >= 0) tab[wid] = hit;
        if (__any(hit >= 0)) break;  // whole wave exits together
    }
}

// 32 lanes per (b,g) pair copy one K=128 emb row (float4 = 16B/lane).
__global__ void gather_emb(const float* __restrict__ emb,
                           const int* __restrict__ word_idx,
                           const int* __restrict__ tab,
                           float* __restrict__ out) {
    int pair = blockIdx.x * 8 + (threadIdx.x >> 5);  // 8 pairs per 256-thread block
    int lane = threadIdx.x & 31;
    int b = pair / G;
    int g = pair - b * G;
    int w = word_idx[b];
    int idx = tab[g * V + w];
    float4 val = *(const float4*)(emb + (size_t)idx * K + lane * 4);
    *(float4*)(out + (size_t)pair * K + lane * 4) = val;
}

extern "C" void kernel_launch(void* const* d_in, const int* in_sizes, int n_in,
                              void* d_out, int out_size, void* d_ws, size_t ws_size,
                              hipStream_t stream) {
    const float* input = (const float*)d_in[0];  // [B, V]
    const float* perms = (const float*)d_in[1];  // [G, V, V]
    const float* emb   = (const float*)d_in[2];  // [V, K]
    float* out = (float*)d_out;                  // [B, G, K]

    int* ws       = (int*)d_ws;
    int* word_idx = ws;              // B ints
    int* needed   = ws + B;          // V ints
    int* tab      = ws + B + V;      // G*V ints

    zero_needed<<<(V + 255) / 256, 256, 0, stream>>>(needed);
    find_word_idx<<<B, 256, 0, stream>>>(input, word_idx, needed);
    // G*V waves, 4 waves (256 threads) per block
    scan_perms<<<(G * V) / 4, 256, 0, stream>>>(perms, needed, tab);
    gather_emb<<<(B * G) / 8, 256, 0, stream>>>(emb, word_idx, tab, out);
}

// Round 2
// 911.238 us; speedup vs baseline: 1.0119x; 1.0119x over previous
//
#include <hip/hip_runtime.h>

// Problem constants (from reference): V=2048, G=48, K=128, B=1024
#define V 2048
#define G 48
#define K 128
#define B 1024

// Workspace layout (ints): [0, B) word_idx[b]

// One block (256 threads) per batch row: find the 1.0 in the one-hot input.
// Exactly one thread finds it -> no reduction needed.
__global__ void find_word_idx(const float* __restrict__ input,
                              int* __restrict__ word_idx) {
    int b = blockIdx.x;
    int t = threadIdx.x;
    const float* row = input + (size_t)b * V;
    int base = t * 8;  // 256 threads * 8 floats = 2048
    float4 x0 = *(const float4*)(row + base);
    float4 x1 = *(const float4*)(row + base + 4);
    int hit = -1;
    if      (x0.x > 0.5f) hit = base + 0;
    else if (x0.y > 0.5f) hit = base + 1;
    else if (x0.z > 0.5f) hit = base + 2;
    else if (x0.w > 0.5f) hit = base + 3;
    else if (x1.x > 0.5f) hit = base + 4;
    else if (x1.y > 0.5f) hit = base + 5;
    else if (x1.z > 0.5f) hit = base + 6;
    else if (x1.w > 0.5f) hit = base + 7;
    if (hit >= 0) word_idx[b] = hit;
}

// One wave (64 lanes) per (g, b) pair:
//   1. scan perms[g, word_idx[b], :] for the 1.0 (early exit, expected half row)
//   2. broadcast the found index, gather emb row, write out[b, g, :]
// g-major wave ordering keeps duplicate-word rows within a g temporally close
// for L2/L3 reuse (touched perms footprint ~175 MB < 256 MB L3).
__global__ void scan_and_gather(const float* __restrict__ perms,
                                const float* __restrict__ emb,
                                const int* __restrict__ word_idx,
                                float* __restrict__ out) {
    int wid  = blockIdx.x * 4 + (threadIdx.x >> 6);  // 4 waves per 256-thread block
    int lane = threadIdx.x & 63;
    int g = wid >> 10;        // / B
    int b = wid & (B - 1);    // % B
    int w = word_idx[b];
    const float* row = perms + ((size_t)g * V + (size_t)w) * V;

    int idx = -1;
    // 2048 floats, 64 lanes * float4 = 256 floats per iteration, 8 iters.
    for (int it = 0; it < 8; ++it) {
        int base = it * 256 + lane * 4;
        float4 x = *(const float4*)(row + base);
        int hit = -1;
        if      (x.x > 0.5f) hit = base + 0;
        else if (x.y > 0.5f) hit = base + 1;
        else if (x.z > 0.5f) hit = base + 2;
        else if (x.w > 0.5f) hit = base + 3;
        unsigned long long m = __ballot(hit >= 0);
        if (m) {
            int src = (int)__builtin_ctzll(m);
            idx = __shfl(hit, src);
            break;
        }
    }

    // Fused embedding gather: 64 lanes * float2 = 128 floats = one emb row.
    float2 e = *(const float2*)(emb + (size_t)idx * K + lane * 2);
    *(float2*)(out + ((size_t)b * G + g) * K + lane * 2) = e;
}

extern "C" void kernel_launch(void* const* d_in, const int* in_sizes, int n_in,
                              void* d_out, int out_size, void* d_ws, size_t ws_size,
                              hipStream_t stream) {
    const float* input = (const float*)d_in[0];  // [B, V]
    const float* perms = (const float*)d_in[1];  // [G, V, V]
    const float* emb   = (const float*)d_in[2];  // [V, K]
    float* out = (float*)d_out;                  // [B, G, K]

    int* word_idx = (int*)d_ws;  // B ints

    find_word_idx<<<B, 256, 0, stream>>>(input, word_idx);
    // G*B waves, 4 waves (256 threads) per block
    scan_and_gather<<<(G * B) / 4, 256, 0, stream>>>(perms, emb, word_idx, out);
}